// Round 8
// baseline (37874.411 us; speedup 1.0000x reference)
//
#include <hip/hip_runtime.h>
#include <math.h>

#define BB 32
#define TT 500
#define HH 640
#define VV 1024
#define NWG 128      // 32 groups (batches) x 4 slice-WGs

typedef float f32x4 __attribute__((ext_vector_type(4)));
typedef unsigned int u32x2 __attribute__((ext_vector_type(2)));

// ws layout (float offsets)
//  ENC    : 0           (16000*640 = 10,240,000)
//  EW     : 10,240,000  (1024*2560 = 2,621,440) -> 12,861,440
//  h      : 12,861,440  (32*640 = 20,480) -> 12,881,920
//  Tt     : 12,881,920  (20,480) -> 12,902,400
//  slots  : 12,902,400  (128 lines x 32 u32 = 4,096) -> 12,906,496
//  flags  : 12,906,496  (128 lines x 32 u32 = 4,096) -> 12,910,592
//  scores : 12,910,592  (64) -> 12,910,656
//  WTk    : 12,910,656  (640*3200 = 2,048,000) -> 14,958,656   [k][R] permuted cat
// total 14,958,656 floats = 59.8 MB

__device__ __forceinline__ float sigf(float x) { return 1.0f / (1.0f + expf(-x)); }

__device__ __forceinline__ unsigned int fkey(float x) {
    unsigned int u = __float_as_uint(x);
    return (u & 0x80000000u) ? ~u : (u | 0x80000000u);
}

__device__ __forceinline__ unsigned long long shflxor_u64(unsigned long long v, int m) {
    unsigned int lo = (unsigned int)v, hi = (unsigned int)(v >> 32);
    lo = (unsigned int)__shfl_xor((int)lo, m);
    hi = (unsigned int)__shfl_xor((int)hi, m);
    return ((unsigned long long)hi << 32) | lo;
}

// coherent (IC-level) ops, proven in R5/R7
__device__ __forceinline__ void stg1_sc(float* p, float v) {
    asm volatile("global_store_dword %0, %1, off sc0 sc1" :: "v"(p), "v"(v) : "memory");
}
__device__ __forceinline__ void stg4_sc(float* p, f32x4 v) {
    asm volatile("global_store_dwordx4 %0, %1, off sc0 sc1" :: "v"(p), "v"(v) : "memory");
}
__device__ __forceinline__ void stg2u_sc(unsigned int* p, unsigned long long v) {
    u32x2 uv; uv.x = (unsigned int)v; uv.y = (unsigned int)(v >> 32);
    asm volatile("global_store_dwordx2 %0, %1, off sc0 sc1" :: "v"(p), "v"(uv) : "memory");
}
__device__ __forceinline__ f32x4 ldg4_sc(const float* p) {
    f32x4 r;
    asm volatile("global_load_dwordx4 %0, %1, off sc0 sc1\n\ts_waitcnt vmcnt(0)"
                 : "=&v"(r) : "v"(p) : "memory");
    return r;
}

// C[M,N] = A[M,K] @ B[K,N] + bias[N]
__global__ __launch_bounds__(256) void gemm_bias_kernel(
    const float* __restrict__ A, const float* __restrict__ Bm,
    const float* __restrict__ bias, float* __restrict__ C,
    int M, int N, int K)
{
    __shared__ float As[16][65];
    __shared__ float Bs[16][64];
    int tid = threadIdx.x;
    int m0 = blockIdx.y * 64, n0 = blockIdx.x * 64;
    int ar = tid >> 2, ac = (tid & 3) * 4;
    int br4 = (tid >> 6) * 4, bc = tid & 63;
    int ty = tid >> 4, tx = tid & 15;
    float acc[4][4] = {};
    for (int k0 = 0; k0 < K; k0 += 16) {
        float4 av = *(const float4*)(A + (long)(m0 + ar) * K + k0 + ac);
        As[ac + 0][ar] = av.x; As[ac + 1][ar] = av.y;
        As[ac + 2][ar] = av.z; As[ac + 3][ar] = av.w;
#pragma unroll
        for (int i = 0; i < 4; ++i)
            Bs[br4 + i][bc] = Bm[(long)(k0 + br4 + i) * N + n0 + bc];
        __syncthreads();
#pragma unroll
        for (int kk = 0; kk < 16; ++kk) {
            float a[4], b[4];
#pragma unroll
            for (int i = 0; i < 4; ++i) a[i] = As[kk][ty * 4 + i];
#pragma unroll
            for (int j = 0; j < 4; ++j) b[j] = Bs[kk][tx * 4 + j];
#pragma unroll
            for (int i = 0; i < 4; ++i)
#pragma unroll
                for (int j = 0; j < 4; ++j)
                    acc[i][j] = fmaf(a[i], b[j], acc[i][j]);
        }
        __syncthreads();
    }
#pragma unroll
    for (int i = 0; i < 4; ++i)
#pragma unroll
        for (int j = 0; j < 4; ++j)
            C[(long)(m0 + ty * 4 + i) * N + n0 + tx * 4 + j] =
                acc[i][j] + bias[n0 + tx * 4 + j];
}

// WTk[k][R]: R = s*800 + r; r<160 -> W_dec[k][s*160+r];
// else rr=r-160, gate=rr&3, jj=rr>>2 -> W_hh[k][gate*640 + s*160 + jj]
__global__ __launch_bounds__(256) void wtk_kernel(const float* __restrict__ Wdec,
                                                  const float* __restrict__ Whh,
                                                  float* __restrict__ WTk)
{
    __shared__ float Ldec[640];
    __shared__ float Lhh[2560];
    int k = blockIdx.x, tid = threadIdx.x;
    for (int i = tid; i < 640; i += 256)  Ldec[i] = Wdec[(long)k * 640 + i];
    for (int i = tid; i < 2560; i += 256) Lhh[i]  = Whh[(long)k * 2560 + i];
    __syncthreads();
    for (int R = tid; R < 3200; R += 256) {
        int s = R / 800, r = R % 800;
        float v;
        if (r < 160) v = Ldec[s * 160 + r];
        else { int rr = r - 160; v = Lhh[(rr & 3) * 640 + s * 160 + (rr >> 2)]; }
        WTk[(long)k * 3200 + R] = v;
    }
}

__global__ void init_kernel(const float* __restrict__ EW, float* __restrict__ h,
                            float* __restrict__ scores,
                            unsigned int* __restrict__ flags)
{
    int tid = threadIdx.x;
    for (int j = tid; j < HH; j += 256) {
        float gi = EW[j], gg = EW[1280 + j], go = EW[1920 + j];
        float c1 = sigf(gi) * tanhf(gg);
        float h1 = sigf(go) * tanhf(c1);
        for (int b = 0; b < BB; ++b) h[b * 640 + j] = h1;
    }
    if (tid < 32) scores[tid] = 0.f;
    for (int i = tid; i < 128 * 32; i += 256) flags[i] = 0u;
}

// One batch per 4-WG group; zero global syncs.
__global__ __launch_bounds__(512, 1) void decode_chain(
    const float* __restrict__ ENC, const float* __restrict__ EW,
    const float* __restrict__ WTk, const float* __restrict__ Wout,
    const float* __restrict__ bout,
    float* __restrict__ h, float* __restrict__ Tt,
    unsigned int* __restrict__ slots, unsigned int* __restrict__ flags,
    float* __restrict__ scores, float* __restrict__ out)
{
    __shared__ float Sh[640];
    __shared__ float St[640];
    __shared__ float U[800];
    __shared__ unsigned long long rpk[8];
    __shared__ float rss[8];
    __shared__ unsigned long long pks4[4];
    __shared__ float ss4[4];

    int w = blockIdx.x, tid = threadIdx.x;
    int g = w >> 2, s = w & 3;
    float* hb = h + g * 640;
    float* Tb = Tt + g * 640;
    unsigned int* myflag = flags + (g * 4 + s) * 32;
    unsigned int* gflag  = flags + g * 4 * 32;
    unsigned int* myslot = slots + (g * 4 + s) * 32;
    unsigned int* gslot  = slots + g * 4 * 32;

    // c-state lives in a register: thread tid<160 owns j = s*160+tid
    float creg = 0.f;
    if (tid < 160) {
        int j = s * 160 + tid;
        creg = sigf(EW[j]) * tanhf(EW[1280 + j]);
    }
    float score = 0.f;

    for (int t = 0; t < TT; ++t) {
        // ---- wait h ready (flags >= 3t), stage h[g] ----
        if (tid < 4) {
            unsigned int tgt = 3u * (unsigned)t;
            while (__hip_atomic_load(gflag + tid * 32, __ATOMIC_RELAXED,
                                     __HIP_MEMORY_SCOPE_AGENT) < tgt)
                __builtin_amdgcn_s_sleep(2);
        }
        __syncthreads();
        if (tid < 160) {
            f32x4 v = ldg4_sc(hb + tid * 4);
            *(f32x4*)&Sh[tid * 4] = v;
        }
        __syncthreads();

        // ---- A: u = h @ [W_dec|W_hh] slice (800 cols, k-major coalesced) ----
        for (int c = tid; c < 800; c += 512) {
            const float* wp = WTk + (s * 800 + c);
            float acc = 0.f;
#pragma unroll 8
            for (int k = 0; k < 640; ++k)
                acc = fmaf(Sh[k], wp[(long)k * 3200], acc);
            if (c < 160)
                U[c] = tanhf(ENC[((long)g * TT + t) * 640 + s * 160 + c] + acc);
            else
                U[c] = acc;        // gate pre-activation (i,f,g,o interleaved per j)
        }
        __syncthreads();
        if (tid < 40) {
            f32x4 v;
            v.x = U[tid*4]; v.y = U[tid*4+1]; v.z = U[tid*4+2]; v.w = U[tid*4+3];
            stg4_sc(Tb + s * 160 + tid * 4, v);
        }
        asm volatile("s_waitcnt vmcnt(0)" ::: "memory");
        __syncthreads();
        if (tid == 0)
            __hip_atomic_store(myflag, 3u*t + 1u, __ATOMIC_RELAXED,
                               __HIP_MEMORY_SCOPE_AGENT);

        // ---- wait Tt (>= 3t+1), stage, B: logits slice + partial argmax ----
        if (tid < 4) {
            unsigned int tgt = 3u * (unsigned)t + 1u;
            while (__hip_atomic_load(gflag + tid * 32, __ATOMIC_RELAXED,
                                     __HIP_MEMORY_SCOPE_AGENT) < tgt)
                __builtin_amdgcn_s_sleep(2);
        }
        __syncthreads();
        if (tid < 160) {
            f32x4 v = ldg4_sc(Tb + tid * 4);
            *(f32x4*)&St[tid * 4] = v;
        }
        __syncthreads();
        {
            unsigned long long pk = 0ull; float sexp = 0.f;
            if (tid < 256) {
                int v = s * 256 + tid;
                const float* wp = Wout + v;     // W_out is [k][1024] already
                float acc = 0.f;
#pragma unroll 8
                for (int k = 0; k < 640; ++k)
                    acc = fmaf(St[k], wp[(long)k * 1024], acc);
                float logit = acc + bout[v];
                sexp = expf(logit);
                pk = ((unsigned long long)fkey(logit) << 32) | (unsigned)(1023 - v);
            }
#pragma unroll
            for (int m = 1; m <= 32; m <<= 1) {
                unsigned long long o = shflxor_u64(pk, m);
                if (o > pk) pk = o;
                sexp += __shfl_xor(sexp, m);
            }
            if ((tid & 63) == 0) { rpk[tid >> 6] = pk; rss[tid >> 6] = sexp; }
            __syncthreads();
            if (tid == 0) {
                unsigned long long m0 = rpk[0]; float s0 = rss[0];
#pragma unroll
                for (int i = 1; i < 8; ++i) { if (rpk[i] > m0) m0 = rpk[i]; s0 += rss[i]; }
                stg2u_sc(myslot, m0);
                stg1_sc((float*)(myslot + 2), s0);
            }
        }
        asm volatile("s_waitcnt vmcnt(0)" ::: "memory");
        __syncthreads();
        if (tid == 0)
            __hip_atomic_store(myflag, 3u*t + 2u, __ATOMIC_RELAXED,
                               __HIP_MEMORY_SCOPE_AGENT);

        // ---- wait slots (>= 3t+2), replicated reduce + LSTM update ----
        if (tid < 4) {
            unsigned int tgt = 3u * (unsigned)t + 2u;
            while (__hip_atomic_load(gflag + tid * 32, __ATOMIC_RELAXED,
                                     __HIP_MEMORY_SCOPE_AGENT) < tgt)
                __builtin_amdgcn_s_sleep(2);
        }
        __syncthreads();
        if (tid < 4) {
            const unsigned int* lp = gslot + tid * 32;
            u32x2 mv; float sv;
            asm volatile(
                "global_load_dwordx2 %0, %2, off sc0 sc1\n\t"
                "global_load_dword   %1, %3, off sc0 sc1\n\t"
                "s_waitcnt vmcnt(0)"
                : "=&v"(mv), "=&v"(sv)
                : "v"(lp), "v"(lp + 2)
                : "memory");
            pks4[tid] = ((unsigned long long)mv.y << 32) | mv.x;
            ss4[tid] = sv;
        }
        __syncthreads();
        unsigned long long mm = pks4[0]; float ssum = ss4[0];
#pragma unroll
        for (int i = 1; i < 4; ++i) { if (pks4[i] > mm) mm = pks4[i]; ssum += ss4[i]; }
        int tok = 1023 - (int)(mm & 0xFFFFFFFFu);
        int emit = (tok != 0);
        if (s == 0 && tid == 0) {
            out[g * TT + t] = (float)tok;
            if (emit) {
                unsigned int key = (unsigned int)(mm >> 32);
                unsigned int u = (key & 0x80000000u) ? (key ^ 0x80000000u) : ~key;
                score += __uint_as_float(u) - logf(ssum);
            }
        }
        if (emit && tid < 160) {
            int j = s * 160 + tid;
            const float* ew = EW + (long)tok * 2560;
            float gi = U[160 + tid * 4 + 0] + ew[j];
            float gf = U[160 + tid * 4 + 1] + ew[640 + j];
            float gg = U[160 + tid * 4 + 2] + ew[1280 + j];
            float go = U[160 + tid * 4 + 3] + ew[1920 + j];
            float cn = sigf(gf) * creg + sigf(gi) * tanhf(gg);
            float hn = sigf(go) * tanhf(cn);
            creg = cn;
            stg1_sc(hb + j, hn);
        }
        asm volatile("s_waitcnt vmcnt(0)" ::: "memory");
        __syncthreads();
        if (tid == 0)
            __hip_atomic_store(myflag, 3u*t + 3u, __ATOMIC_RELAXED,
                               __HIP_MEMORY_SCOPE_AGENT);
    }

    if (s == 0 && tid == 0) scores[g] = score;
}

__global__ void epilogue_kernel(const float* __restrict__ scores,
                                float* __restrict__ out)
{
    if (threadIdx.x == 0) {
        float sum = 0.f;
        for (int b = 0; b < 32; ++b) sum += expf(scores[b]);
        out[16000] = sum / 32.0f;
    }
}

extern "C" void kernel_launch(void* const* d_in, const int* in_sizes, int n_in,
                              void* d_out, int out_size, void* d_ws, size_t ws_size,
                              hipStream_t stream)
{
    const float* X     = (const float*)d_in[0];
    const float* E     = (const float*)d_in[1];
    const float* W_ih  = (const float*)d_in[2];
    const float* W_hh  = (const float*)d_in[3];
    const float* b_l   = (const float*)d_in[4];
    const float* W_enc = (const float*)d_in[5];
    const float* W_dec = (const float*)d_in[6];
    const float* b_j   = (const float*)d_in[7];
    const float* W_out = (const float*)d_in[8];
    const float* b_out = (const float*)d_in[9];

    float* ws  = (float*)d_ws;
    float* ENC = ws;
    float* EW  = ws + 10240000;
    float* h   = ws + 12861440;
    float* Tt  = ws + 12881920;
    unsigned int* slots = (unsigned int*)(ws + 12902400);
    unsigned int* flags = (unsigned int*)(ws + 12906496);
    float* scores = ws + 12910592;
    float* WTk = ws + 12910656;
    float* out = (float*)d_out;

    gemm_bias_kernel<<<dim3(10, 250), 256, 0, stream>>>(X, W_enc, b_j, ENC, 16000, 640, 640);
    gemm_bias_kernel<<<dim3(40, 16), 256, 0, stream>>>(E, W_ih, b_l, EW, 1024, 2560, 640);
    wtk_kernel<<<640, 256, 0, stream>>>(W_dec, W_hh, WTk);
    init_kernel<<<1, 256, 0, stream>>>(EW, h, scores, flags);

    void* args[] = {
        (void*)&ENC, (void*)&EW, (void*)&WTk, (void*)&W_out,
        (void*)&b_out, (void*)&h, (void*)&Tt, (void*)&slots,
        (void*)&flags, (void*)&scores, (void*)&out
    };
    hipLaunchCooperativeKernel((const void*)decode_chain, dim3(NWG), dim3(512),
                               args, 0, stream);
    epilogue_kernel<<<1, 64, 0, stream>>>(scores, out);
}

// Round 11
// 25630.768 us; speedup vs baseline: 1.4777x; 1.4777x over previous
//
#include <hip/hip_runtime.h>
#include <math.h>

#define BB 32
#define TT 500
#define HH 640
#define VV 1024
#define NWG 100

typedef float f32x4 __attribute__((ext_vector_type(4)));
typedef float f32x2 __attribute__((ext_vector_type(2)));
typedef unsigned int u32x2 __attribute__((ext_vector_type(2)));

// ws layout (float offsets)
//  ENC    : 0            (16000*640 = 10,240,000)
//  EW     : 10,240,000   (1024*2560 = 2,621,440)  -> 12,861,440
//  hring  : 12,861,440   (501*20480 = 10,260,480) -> 23,121,920  write-once ring
//  tring  : 23,121,920   (500*20480 = 10,240,000) -> 33,361,920  write-once ring
//  cst    : 33,361,920   (20,480)                 -> 33,382,400
//  G      : 33,382,400   (81,920)                 -> 33,464,320
//  pmax   : 33,464,320   (32*128 u64 = 8,192 f)   -> 33,472,512
//  psum   : 33,472,512   (4,096)                  -> 33,476,608
//  scores : 33,476,608   (64)                     -> 33,476,672
//  arrive : 33,476,672   (100*32 = 3,200)         -> 33,479,872
//  release: 33,479,872   (3,200)                  -> 33,483,072
//  WcatT  : 33,483,072   (2,048,000)              -> 35,531,072
//  WoT    : 35,531,072   (655,360)                -> 36,186,432  (144.7 MB)

__device__ __forceinline__ float sigf(float x) { return 1.0f / (1.0f + expf(-x)); }

__device__ __forceinline__ unsigned int fkey(float x) {
    unsigned int u = __float_as_uint(x);
    return (u & 0x80000000u) ? ~u : (u | 0x80000000u);
}

__device__ __forceinline__ unsigned long long shflxor_u64(unsigned long long v, int m) {
    unsigned int lo = (unsigned int)v, hi = (unsigned int)(v >> 32);
    lo = (unsigned int)__shfl_xor((int)lo, m);
    hi = (unsigned int)__shfl_xor((int)hi, m);
    return ((unsigned long long)hi << 32) | lo;
}

// ---- coherent (memory-level) stores for cross-WG data; proven R5/R7 ----
__device__ __forceinline__ void stg1_sc(float* p, float v) {
    asm volatile("global_store_dword %0, %1, off sc0 sc1" :: "v"(p), "v"(v) : "memory");
}
__device__ __forceinline__ void stg2_sc(float* p, f32x2 v) {
    asm volatile("global_store_dwordx2 %0, %1, off sc0 sc1" :: "v"(p), "v"(v) : "memory");
}
__device__ __forceinline__ void stg4_sc(float* p, f32x4 v) {
    asm volatile("global_store_dwordx4 %0, %1, off sc0 sc1" :: "v"(p), "v"(v) : "memory");
}
__device__ __forceinline__ void stg2u_sc(unsigned long long* p, unsigned long long v) {
    u32x2 uv; uv.x = (unsigned int)v; uv.y = (unsigned int)(v >> 32);
    asm volatile("global_store_dwordx2 %0, %1, off sc0 sc1" :: "v"(p), "v"(uv) : "memory");
}

// Fence-free distributed grid barrier (validated R3/R5/R7).
__device__ __forceinline__ void gbar(unsigned int* arrive, unsigned int* release,
                                     int w, int tid, unsigned int k) {
    asm volatile("s_waitcnt vmcnt(0)" ::: "memory");
    __syncthreads();
    if (w == 0) {
        if (tid > 0 && tid < NWG)
            while (__hip_atomic_load(&arrive[tid * 32], __ATOMIC_RELAXED,
                                     __HIP_MEMORY_SCOPE_AGENT) < k)
                __builtin_amdgcn_s_sleep(2);
        __syncthreads();
        if (tid > 0 && tid < NWG)
            __hip_atomic_store(&release[tid * 32], k, __ATOMIC_RELAXED,
                               __HIP_MEMORY_SCOPE_AGENT);
    } else {
        if (tid == 0) {
            __hip_atomic_store(&arrive[w * 32], k, __ATOMIC_RELAXED,
                               __HIP_MEMORY_SCOPE_AGENT);
            while (__hip_atomic_load(&release[w * 32], __ATOMIC_RELAXED,
                                     __HIP_MEMORY_SCOPE_AGENT) < k)
                __builtin_amdgcn_s_sleep(2);
        }
        __syncthreads();
    }
}

// C[M,N] = A[M,K] @ B[K,N] + bias[N]
__global__ __launch_bounds__(256) void gemm_bias_kernel(
    const float* __restrict__ A, const float* __restrict__ Bm,
    const float* __restrict__ bias, float* __restrict__ C,
    int M, int N, int K)
{
    __shared__ float As[16][65];
    __shared__ float Bs[16][64];
    int tid = threadIdx.x;
    int m0 = blockIdx.y * 64, n0 = blockIdx.x * 64;
    int ar = tid >> 2, ac = (tid & 3) * 4;
    int br4 = (tid >> 6) * 4, bc = tid & 63;
    int ty = tid >> 4, tx = tid & 15;
    float acc[4][4] = {};
    for (int k0 = 0; k0 < K; k0 += 16) {
        float4 av = *(const float4*)(A + (long)(m0 + ar) * K + k0 + ac);
        As[ac + 0][ar] = av.x; As[ac + 1][ar] = av.y;
        As[ac + 2][ar] = av.z; As[ac + 3][ar] = av.w;
#pragma unroll
        for (int i = 0; i < 4; ++i)
            Bs[br4 + i][bc] = Bm[(long)(k0 + br4 + i) * N + n0 + bc];
        __syncthreads();
#pragma unroll
        for (int kk = 0; kk < 16; ++kk) {
            float a[4], b[4];
#pragma unroll
            for (int i = 0; i < 4; ++i) a[i] = As[kk][ty * 4 + i];
#pragma unroll
            for (int j = 0; j < 4; ++j) b[j] = Bs[kk][tx * 4 + j];
#pragma unroll
            for (int i = 0; i < 4; ++i)
#pragma unroll
                for (int j = 0; j < 4; ++j)
                    acc[i][j] = fmaf(a[i], b[j], acc[i][j]);
        }
        __syncthreads();
    }
#pragma unroll
    for (int i = 0; i < 4; ++i)
#pragma unroll
        for (int j = 0; j < 4; ++j)
            C[(long)(m0 + ty * 4 + i) * N + n0 + tx * 4 + j] =
                acc[i][j] + bias[n0 + tx * 4 + j];
}

// WcatT[c][k] = c<640 ? Wdec[k][c] : Whh[k][c-640]
__global__ void transpose_cat_kernel(const float* __restrict__ Wdec,
                                     const float* __restrict__ Whh,
                                     float* __restrict__ WcatT)
{
    int c = blockIdx.x;
    const float* src; long stride;
    if (c < 640) { src = Wdec + c; stride = 640; }
    else         { src = Whh + (c - 640); stride = 2560; }
    for (int k = threadIdx.x; k < 640; k += 256)
        WcatT[(long)c * 640 + k] = src[(long)k * stride];
}

// WoT[v][k] = Wout[k][v]
__global__ void transpose_out_kernel(const float* __restrict__ Wout,
                                     float* __restrict__ WoT)
{
    int v = blockIdx.x;
    for (int k = threadIdx.x; k < 640; k += 256)
        WoT[(long)v * 640 + k] = Wout[(long)k * 1024 + v];
}

__global__ void init_kernel(const float* __restrict__ EW, float* __restrict__ hring,
                            float* __restrict__ cst, float* __restrict__ scores,
                            unsigned int* __restrict__ arrive,
                            unsigned int* __restrict__ release,
                            unsigned long long* __restrict__ pmax,
                            float* __restrict__ psum)
{
    int tid = threadIdx.x;
    for (int j = tid; j < HH; j += 256) {
        float gi = EW[j], gg = EW[1280 + j], go = EW[1920 + j];
        float c1 = sigf(gi) * tanhf(gg);
        float h1 = sigf(go) * tanhf(c1);
        for (int b = 0; b < BB; ++b) {
            hring[b * 640 + j] = h1;      // ring slot 0
            cst[b * 640 + j] = c1;
        }
    }
    if (tid < 32) scores[tid] = 0.f;
    if (tid < NWG) { arrive[tid * 32] = 0u; release[tid * 32] = 0u; }
    for (int i = tid; i < 32 * 128; i += 256) { pmax[i] = 0ull; psum[i] = 0.f; }
}

// Dynamic LDS (floats): S[32][644] 0..20608 ; P[8][32][36] 20608..29824
extern __shared__ float lds[];

__global__ __launch_bounds__(256, 1) void decode_kernel(
    const float* __restrict__ ENC, const float* __restrict__ EW,
    const float* __restrict__ WcatT, const float* __restrict__ WoT,
    const float* __restrict__ bout,
    float* __restrict__ hring, float* __restrict__ cst,
    float* __restrict__ tring, float* __restrict__ G,
    unsigned long long* __restrict__ pmax, float* __restrict__ psum,
    float* __restrict__ scores, float* __restrict__ out,
    unsigned int* arrive, unsigned int* release)
{
    float* S = lds;
    float* P = lds + 20608;
    __shared__ int s_tok, s_emit;

    int w = blockIdx.x, tid = threadIdx.x;

    // staging assignment: thread copies 80 contiguous floats (plain, L2-cached)
    int srow = tid >> 3, scol = (tid & 7) * 80;
    int sgl  = srow * 640 + scol;
    int sll  = srow * 644 + scol;

    // phase-A decomposition: 32 cols/WG; thread = (ks 8) x (bg 8 -> 4 b) x (cg 4 -> 8 cols)
    int ks = tid >> 5, bg = (tid >> 2) & 7, cg = tid & 3;
    int b0 = bg * 4, c0 = cg * 8;
    int C0 = w * 32;
    const float* wbase = WcatT + ((long)(C0 + c0)) * 640 + ks * 80;

    // phase-B decomposition: thread = (b 32) x (k-slice 8 of 80)
    int pb = tid >> 3, pk8 = (tid & 7) * 80;
    int V0 = w * 10 + (w < 24 ? w : 24);
    int nv = 10 + (w < 24 ? 1 : 0);

    float score = 0.f;
    unsigned int bk = 0;

    for (int t = 0; t < TT; ++t) {
        const float* hslot = hring + (long)t * 20480;
        float* tslot = tring + (long)t * 20480;

        // ============ Phase A: u = h @ [W_dec|W_hh]; Tt / G ============
        {
            const float* hsrc = hslot + sgl;
            f32x4* d = (f32x4*)&S[sll];
#pragma unroll
            for (int i = 0; i < 20; ++i)
                d[i] = *(const f32x4*)(hsrc + i * 4);
        }
        __syncthreads();
        {
            const float* sb = &S[b0 * 644 + ks * 80];
            float acc[4][8] = {};
            for (int kk = 0; kk < 80; kk += 4) {
                float4 hv[4];
#pragma unroll
                for (int i = 0; i < 4; ++i)
                    hv[i] = *(const float4*)(sb + i * 644 + kk);
#pragma unroll
                for (int j = 0; j < 8; ++j) {
                    float4 wv = *(const float4*)(wbase + (long)j * 640 + kk);
#pragma unroll
                    for (int i = 0; i < 4; ++i) {
                        acc[i][j] = fmaf(hv[i].x, wv.x, acc[i][j]);
                        acc[i][j] = fmaf(hv[i].y, wv.y, acc[i][j]);
                        acc[i][j] = fmaf(hv[i].z, wv.z, acc[i][j]);
                        acc[i][j] = fmaf(hv[i].w, wv.w, acc[i][j]);
                    }
                }
            }
#pragma unroll
            for (int i = 0; i < 4; ++i) {
                float4 v0, v1;
                v0.x = acc[i][0]; v0.y = acc[i][1]; v0.z = acc[i][2]; v0.w = acc[i][3];
                v1.x = acc[i][4]; v1.y = acc[i][5]; v1.z = acc[i][6]; v1.w = acc[i][7];
                *(float4*)&P[ks * 1152 + (b0 + i) * 36 + c0]     = v0;
                *(float4*)&P[ks * 1152 + (b0 + i) * 36 + c0 + 4] = v1;
            }
        }
        __syncthreads();
        {
            int rb = tid >> 3, rc = (tid & 7) * 4;
            float r0 = 0.f, r1 = 0.f, r2 = 0.f, r3 = 0.f;
#pragma unroll
            for (int kr = 0; kr < 8; ++kr) {
                float4 pv = *(const float4*)&P[kr * 1152 + rb * 36 + rc];
                r0 += pv.x; r1 += pv.y; r2 += pv.z; r3 += pv.w;
            }
            int gc = C0 + rc;
            f32x4 ov;
            if (w < 20) {
                float4 ev = *(const float4*)&ENC[((long)rb * TT + t) * 640 + gc];
                ov.x = tanhf(ev.x + r0); ov.y = tanhf(ev.y + r1);
                ov.z = tanhf(ev.z + r2); ov.w = tanhf(ev.w + r3);
                stg4_sc(tslot + rb * 640 + gc, ov);
            } else {
                ov.x = r0; ov.y = r1; ov.z = r2; ov.w = r3;
                stg4_sc(&G[rb * 2560 + gc - 640], ov);
            }
        }
        gbar(arrive, release, w, tid, ++bk);

        // ============ Phase B: logits + per-WG argmax/sumexp ============
        {
            const float* tsrc = tslot + sgl;
            f32x4* d = (f32x4*)&S[sll];
#pragma unroll
            for (int i = 0; i < 20; ++i)
                d[i] = *(const f32x4*)(tsrc + i * 4);
        }
        __syncthreads();
        {
            const float* tb = &S[pb * 644 + pk8];
            unsigned long long best = 0ull; float sex = 0.f;
            for (int vi = 0; vi < nv; ++vi) {
                int v = V0 + vi;
                const float* wb = WoT + (long)v * 640 + pk8;
                float acc = 0.f;
                for (int kk = 0; kk < 80; kk += 4) {
                    float4 tv = *(const float4*)(tb + kk);
                    float4 wv = *(const float4*)(wb + kk);
                    acc = fmaf(tv.x, wv.x, acc);
                    acc = fmaf(tv.y, wv.y, acc);
                    acc = fmaf(tv.z, wv.z, acc);
                    acc = fmaf(tv.w, wv.w, acc);
                }
                acc += __shfl_xor(acc, 1);
                acc += __shfl_xor(acc, 2);
                acc += __shfl_xor(acc, 4);
                if ((tid & 7) == 0) {
                    float logit = acc + bout[v];
                    sex += expf(logit);
                    unsigned long long q =
                        ((unsigned long long)fkey(logit) << 32) | (unsigned)(1023 - v);
                    if (q > best) best = q;
                }
            }
            if ((tid & 7) == 0) {
                stg2u_sc(pmax + pb * 128 + w, best);
                stg1_sc(psum + pb * 128 + w, sex);
            }
        }
        gbar(arrive, release, w, tid, ++bk);

        // ============ Phase C: reduce, emit, LSTM update ============
        if (w < 32) {
            int b = w;
            if (tid < 64) {
                u32x2 m1, m2; float s1, s2;
                asm volatile(
                    "global_load_dwordx2 %0, %4, off sc0 sc1\n\t"
                    "global_load_dwordx2 %1, %5, off sc0 sc1\n\t"
                    "global_load_dword   %2, %6, off sc0 sc1\n\t"
                    "global_load_dword   %3, %7, off sc0 sc1\n\t"
                    "s_waitcnt vmcnt(0)"
                    : "=&v"(m1), "=&v"(m2), "=&v"(s1), "=&v"(s2)
                    : "v"(pmax + b * 128 + tid), "v"(pmax + b * 128 + 64 + tid),
                      "v"(psum + b * 128 + tid), "v"(psum + b * 128 + 64 + tid)
                    : "memory");
                unsigned long long ma = ((unsigned long long)m1.y << 32) | m1.x;
                unsigned long long mb = ((unsigned long long)m2.y << 32) | m2.x;
                if (mb > ma) ma = mb;
                float s = s1 + s2;
#pragma unroll
                for (int mask = 1; mask <= 32; mask <<= 1) {
                    unsigned long long o = shflxor_u64(ma, mask);
                    if (o > ma) ma = o;
                    s += __shfl_xor(s, mask);
                }
                if (tid == 0) {
                    int tok = 1023 - (int)(ma & 0xFFFFFFFFu);
                    unsigned int key = (unsigned int)(ma >> 32);
                    unsigned int u = (key & 0x80000000u) ? (key ^ 0x80000000u) : ~key;
                    float maxlogit = __uint_as_float(u);
                    int emit = (tok != 0);
                    out[b * TT + t] = (float)tok;
                    if (emit) score += maxlogit - logf(s);
                    s_tok = tok; s_emit = emit;
                }
            }
            __syncthreads();
            float* hnext = hring + (long)(t + 1) * 20480 + b * 640;
            if (tid < 160) {
                int j4 = tid * 4;
                if (s_emit) {
                    const float* gb = G + b * 2560 + j4;
                    f32x4 vi, vf, vg, vo;
                    asm volatile(
                        "global_load_dwordx4 %0, %4, off sc0 sc1\n\t"
                        "global_load_dwordx4 %1, %5, off sc0 sc1\n\t"
                        "global_load_dwordx4 %2, %6, off sc0 sc1\n\t"
                        "global_load_dwordx4 %3, %7, off sc0 sc1\n\t"
                        "s_waitcnt vmcnt(0)"
                        : "=&v"(vi), "=&v"(vf), "=&v"(vg), "=&v"(vo)
                        : "v"(gb), "v"(gb + 640), "v"(gb + 1280), "v"(gb + 1920)
                        : "memory");
                    const float* ew = EW + (long)s_tok * 2560 + j4;
                    float4 ei = *(const float4*)(ew);
                    float4 ef = *(const float4*)(ew + 640);
                    float4 eg = *(const float4*)(ew + 1280);
                    float4 eo = *(const float4*)(ew + 1920);
                    float4 cv = *(const float4*)(cst + b * 640 + j4);
                    float4 cn; f32x4 hn;
                    cn.x = sigf(vf.x + ef.x) * cv.x + sigf(vi.x + ei.x) * tanhf(vg.x + eg.x);
                    cn.y = sigf(vf.y + ef.y) * cv.y + sigf(vi.y + ei.y) * tanhf(vg.y + eg.y);
                    cn.z = sigf(vf.z + ef.z) * cv.z + sigf(vi.z + ei.z) * tanhf(vg.z + eg.z);
                    cn.w = sigf(vf.w + ef.w) * cv.w + sigf(vi.w + ei.w) * tanhf(vg.w + eg.w);
                    hn.x = sigf(vo.x + eo.x) * tanhf(cn.x);
                    hn.y = sigf(vo.y + eo.y) * tanhf(cn.y);
                    hn.z = sigf(vo.z + eo.z) * tanhf(cn.z);
                    hn.w = sigf(vo.w + eo.w) * tanhf(cn.w);
                    *(float4*)(cst + b * 640 + j4) = cn;   // plain: same-WG reuse only
                    stg4_sc(hnext + j4, hn);
                } else {
                    // no emit: carry h forward into the next ring slot
                    f32x4 hv = *(const f32x4*)(hring + (long)t * 20480 + b * 640 + j4);
                    stg4_sc(hnext + j4, hv);
                }
            }
        }
        gbar(arrive, release, w, tid, ++bk);
    }

    if (w < 32 && tid == 0)
        stg1_sc(scores + w, score);
    gbar(arrive, release, w, tid, ++bk);

    if (w == 0 && tid == 0) {
        f32x4 s0,s1,s2,s3,s4,s5,s6,s7;
        asm volatile(
            "global_load_dwordx4 %0, %8, off sc0 sc1\n\t"
            "global_load_dwordx4 %1, %8, off offset:16 sc0 sc1\n\t"
            "global_load_dwordx4 %2, %8, off offset:32 sc0 sc1\n\t"
            "global_load_dwordx4 %3, %8, off offset:48 sc0 sc1\n\t"
            "global_load_dwordx4 %4, %8, off offset:64 sc0 sc1\n\t"
            "global_load_dwordx4 %5, %8, off offset:80 sc0 sc1\n\t"
            "global_load_dwordx4 %6, %8, off offset:96 sc0 sc1\n\t"
            "global_load_dwordx4 %7, %8, off offset:112 sc0 sc1\n\t"
            "s_waitcnt vmcnt(0)"
            : "=&v"(s0),"=&v"(s1),"=&v"(s2),"=&v"(s3),
              "=&v"(s4),"=&v"(s5),"=&v"(s6),"=&v"(s7)
            : "v"(scores) : "memory");
        float sum = expf(s0.x)+expf(s0.y)+expf(s0.z)+expf(s0.w)
                  + expf(s1.x)+expf(s1.y)+expf(s1.z)+expf(s1.w)
                  + expf(s2.x)+expf(s2.y)+expf(s2.z)+expf(s2.w)
                  + expf(s3.x)+expf(s3.y)+expf(s3.z)+expf(s3.w)
                  + expf(s4.x)+expf(s4.y)+expf(s4.z)+expf(s4.w)
                  + expf(s5.x)+expf(s5.y)+expf(s5.z)+expf(s5.w)
                  + expf(s6.x)+expf(s6.y)+expf(s6.z)+expf(s6.w)
                  + expf(s7.x)+expf(s7.y)+expf(s7.z)+expf(s7.w);
        out[16000] = sum / 32.0f;
    }
}

extern "C" void kernel_launch(void* const* d_in, const int* in_sizes, int n_in,
                              void* d_out, int out_size, void* d_ws, size_t ws_size,
                              hipStream_t stream)
{
    const float* X     = (const float*)d_in[0];
    const float* E     = (const float*)d_in[1];
    const float* W_ih  = (const float*)d_in[2];
    const float* W_hh  = (const float*)d_in[3];
    const float* b_l   = (const float*)d_in[4];
    const float* W_enc = (const float*)d_in[5];
    const float* W_dec = (const float*)d_in[6];
    const float* b_j   = (const float*)d_in[7];
    const float* W_out = (const float*)d_in[8];
    const float* b_out = (const float*)d_in[9];

    float* ws  = (float*)d_ws;
    float* ENC   = ws;
    float* EW    = ws + 10240000;
    float* hring = ws + 12861440;
    float* tring = ws + 23121920;
    float* cst   = ws + 33361920;
    float* G     = ws + 33382400;
    unsigned long long* pmax = (unsigned long long*)(ws + 33464320);
    float* psum   = ws + 33472512;
    float* scores = ws + 33476608;
    unsigned int* arrive  = (unsigned int*)(ws + 33476672);
    unsigned int* release = (unsigned int*)(ws + 33479872);
    float* WcatT = ws + 33483072;
    float* WoT   = ws + 35531072;
    float* out = (float*)d_out;

    gemm_bias_kernel<<<dim3(10, 250), 256, 0, stream>>>(X, W_enc, b_j, ENC, 16000, 640, 640);
    gemm_bias_kernel<<<dim3(40, 16), 256, 0, stream>>>(E, W_ih, b_l, EW, 1024, 2560, 640);
    transpose_cat_kernel<<<3200, 256, 0, stream>>>(W_dec, W_hh, WcatT);
    transpose_out_kernel<<<1024, 256, 0, stream>>>(W_out, WoT);
    init_kernel<<<1, 256, 0, stream>>>(EW, hring, cst, scores, arrive, release, pmax, psum);

    void* args[] = {
        (void*)&ENC, (void*)&EW, (void*)&WcatT, (void*)&WoT, (void*)&b_out,
        (void*)&hring, (void*)&cst, (void*)&tring, (void*)&G,
        (void*)&pmax, (void*)&psum, (void*)&scores, (void*)&out,
        (void*)&arrive, (void*)&release
    };
    hipLaunchCooperativeKernel((const void*)decode_kernel, dim3(NWG), dim3(256),
                               args, 119296, stream);
}